// Round 4
// baseline (171.223 us; speedup 1.0000x reference)
//
#include <hip/hip_runtime.h>
#include <math.h>

#define KNN    10
#define NPTS   8192
#define HID    64
#define NF     76
#define Q      16                // queries per wave
#define CAP    64                // pass-2 collection capacity per query
#define F32_INF __uint_as_float(0x7F800000u)

typedef float v2f __attribute__((ext_vector_type(2)));

__device__ __forceinline__ float rl(float v, int lane) {
    return __int_as_float(__builtin_amdgcn_readlane(__float_as_int(v), lane));
}

// ---------------------------------------------------------------------------
// KNN — R18 structure, R21 SGPR queries, R22 packed FP32, R23 change:
// 2-tile-deep software prefetch.
//   Evidence (R22): -19% VALU issue (VALUBusy 81->66%) moved time <1% ->
//   not VALU-throughput-bound. Model: per-SIMD true VALU util ~22%
//   (1-(1-.22)^4 = 64% ~ reported "any-SIMD" 66%); ~78% of cycles are
//   stalls. Dominant stall: per-tile vmcnt wait — prefetch is only 1 tile
//   ahead (~100 own-issue cycles coverage, ~200-400 with wave interleave)
//   vs ~200-600 cyc L2/L3 latency (24KB quarter doesn't stay L1-resident).
//   Fix: 3-stage rotation (cur / next / in-flight): loads for tile ti+2
//   issue at iter ti -> 2 tile bodies of coverage. +6 VGPR, occupancy
//   unchanged. Tile order and all FP chains bit-identical.
// Selection chain untouched (validated 10+ rounds).
// ---------------------------------------------------------------------------
__global__ __launch_bounds__(512) void knn_kernel(const float* __restrict__ cloud,
                                                  unsigned short* __restrict__ knn_idx) {
    __shared__ unsigned long long coll[CAP][33];   // 16.9 KB
    __shared__ float pk[8][Q][17];                 // 8.7 KB
    __shared__ float tau_s[32];
    __shared__ int   cnt[32];

    const int t    = threadIdx.x;
    const int w    = t >> 6;                  // wave 0..7
    const int lane = t & 63;
    const int g    = w >> 2;                  // query group 0..1
    const int h    = w & 3;                   // candidate quarter 0..3
    const int bx   = blockIdx.x;              // 0..1023
    const int b    = bx >> 8;                 // batch
    const int n_base = (bx & 255) * 32 + g * Q;   // batch-local first query of group
    const int lq_base = g * Q;                // block-local query base
    const int cb0 = h * (NPTS / 4);           // candidate base for this wave

    const float* cb = cloud + (size_t)b * NPTS * 3;

    if (t < 32) cnt[t] = 0;                   // visible after barrier 1

    // ---- query coords -> SGPR pairs via readlane (R21/R22) ----
    v2f qx_p[8], qy_p[8], qz_p[8];
    {
        const int ql = n_base + (lane & 15);
        const float lx = cb[ql * 3 + 0];
        const float ly = cb[ql * 3 + 1];
        const float lz = cb[ql * 3 + 2];
#pragma unroll
        for (int j = 0; j < 8; ++j) {
            qx_p[j] = (v2f){ rl(lx, 2 * j), rl(lx, 2 * j + 1) };
            qy_p[j] = (v2f){ rl(ly, 2 * j), rl(ly, 2 * j + 1) };
            qz_p[j] = (v2f){ rl(lz, 2 * j), rl(lz, 2 * j + 1) };
        }
    }

    // ---------------- pass 1: per-lane minima over this quarter ----------------
    v2f vmin2[8];
#pragma unroll
    for (int j = 0; j < 8; ++j) vmin2[j] = (v2f){ F32_INF, F32_INF };

    {
        // 2-deep pipeline: cur (tile ti), n1 (tile ti+1), issue ti+2 each iter
        float cx0 = cb[(cb0 + lane) * 3 + 0];
        float cy0 = cb[(cb0 + lane) * 3 + 1];
        float cz0 = cb[(cb0 + lane) * 3 + 2];
        float nx1 = cb[(cb0 + 64 + lane) * 3 + 0];
        float ny1 = cb[(cb0 + 64 + lane) * 3 + 1];
        float nz1 = cb[(cb0 + 64 + lane) * 3 + 2];
        for (int ti = 0; ti < NPTS / 4 / 64; ++ti) {  // 32 tiles
            const int c2 = cb0 + (((ti + 2) & 31) * 64) + lane;   // wrap: tail reloads, dead
            const float px = cb[c2 * 3 + 0];
            const float py = cb[c2 * 3 + 1];
            const float pz = cb[c2 * 3 + 2];
            const float aw  = fmaf(cz0, cz0, fmaf(cy0, cy0, cx0 * cx0));  // prep expr
            const v2f aw2  = (v2f){ aw, aw };
            const v2f a2x2 = (v2f){ -2.0f * cx0, -2.0f * cx0 };
            const v2f a2y2 = (v2f){ -2.0f * cy0, -2.0f * cy0 };
            const v2f a2z2 = (v2f){ -2.0f * cz0, -2.0f * cz0 };
#pragma unroll
            for (int j = 0; j < 8; ++j) {
                const v2f v = __builtin_elementwise_fma(a2x2, qx_p[j],
                              __builtin_elementwise_fma(a2y2, qy_p[j],
                              __builtin_elementwise_fma(a2z2, qz_p[j], aw2)));
                vmin2[j] = __builtin_elementwise_min(vmin2[j], v);  // self included
            }
            cx0 = nx1; cy0 = ny1; cz0 = nz1;
            nx1 = px;  ny1 = py;  nz1 = pz;
        }
    }

#pragma unroll
    for (int qq = 0; qq < Q; ++qq) {
        float v = vmin2[qq >> 1][qq & 1];
        v = fminf(v, __shfl_xor(v, 32, 64));
        v = fminf(v, __shfl_xor(v, 16, 64));
        if (lane < 16) pk[w][qq][lane] = v;
    }
    __syncthreads();                          // barrier 1: pk + cnt visible

    // h==0 waves: 11th smallest of 64 chunk minima -> tau for group
    if (h == 0) {
        float md[KNN + 1];
#pragma unroll
        for (int s = 0; s <= KNN; ++s) md[s] = F32_INF;
        const int qsel = lane & 15;           // 4-way replicated
#pragma unroll
        for (int cc = 0; cc < 64; ++cc) {
            float d = pk[g * 4 + (cc >> 4)][qsel][cc & 15];
#pragma unroll
            for (int u = 0; u <= KNN; ++u) {
                const float lo = fminf(md[u], d);
                d = fmaxf(md[u], d);
                md[u] = lo;
            }
        }
        if (lane < 16) tau_s[lq_base + lane] = md[KNN] + 1e-3f;
    }
    __syncthreads();                          // barrier 2: tau visible

    float taum[Q];
    {
        const float tv = tau_s[lq_base + (lane & 15)];
#pragma unroll
        for (int qq = 0; qq < Q; ++qq) taum[qq] = rl(tv, qq);   // -> SGPRs
    }

    // ---------------- pass 2: collect hits incl. self (rare) ----------------
    {
        float cx2 = cb[(cb0 + lane) * 3 + 0];
        float cy2 = cb[(cb0 + lane) * 3 + 1];
        float cz2 = cb[(cb0 + lane) * 3 + 2];
        float nx1 = cb[(cb0 + 64 + lane) * 3 + 0];
        float ny1 = cb[(cb0 + 64 + lane) * 3 + 1];
        float nz1 = cb[(cb0 + 64 + lane) * 3 + 2];
        int jcur = cb0 + lane;
        for (int ti = 0; ti < NPTS / 4 / 64; ++ti) {
            const int c2 = cb0 + (((ti + 2) & 31) * 64) + lane;
            const float px = cb[c2 * 3 + 0];
            const float py = cb[c2 * 3 + 1];
            const float pz = cb[c2 * 3 + 2];
            const float aw  = fmaf(cz2, cz2, fmaf(cy2, cy2, cx2 * cx2));
            const v2f aw2  = (v2f){ aw, aw };
            const v2f a2x2 = (v2f){ -2.0f * cx2, -2.0f * cx2 };
            const v2f a2y2 = (v2f){ -2.0f * cy2, -2.0f * cy2 };
            const v2f a2z2 = (v2f){ -2.0f * cz2, -2.0f * cz2 };
#pragma unroll
            for (int j = 0; j < 8; ++j) {
                const v2f v = __builtin_elementwise_fma(a2x2, qx_p[j],
                              __builtin_elementwise_fma(a2y2, qy_p[j],
                              __builtin_elementwise_fma(a2z2, qz_p[j], aw2)));
#pragma unroll
                for (int half = 0; half < 2; ++half) {
                    const int qq = 2 * j + half;
                    if (__builtin_expect(v[half] <= taum[qq], 0)) {
                        // EXACT key: R1-chain d2 expression on identical bits.
                        const float qx = qx_p[j][half];
                        const float qy = qy_p[j][half];
                        const float qz = qz_p[j][half];
                        const float qs = fmaf(qz, qz, fmaf(qy, qy, qx * qx));
                        const float dot = fmaf(cz2, qz, fmaf(cy2, qy, cx2 * qx));
                        const float d2 = fmaf(-2.0f, dot, qs + aw);
                        const unsigned int fb = __float_as_uint(d2);
                        const unsigned int m =
                            fb ^ ((unsigned int)((int)fb >> 31) | 0x80000000u);  // monotone
                        const unsigned long long key =
                            ((unsigned long long)m << 13) | (unsigned long long)(unsigned)jcur;
                        const int slot = atomicAdd(&cnt[lq_base + qq], 1);
                        if (slot < CAP) coll[slot][lq_base + qq] = key;
                    }
                }
            }
            cx2 = nx1; cy2 = ny1; cz2 = nz1;
            nx1 = px;  ny1 = py;  nz1 = pz;
            jcur += 64;
        }
    }
    __syncthreads();

    // ---------------- phase 3: top-11 bubble, filter self by index ----------
    if (t < 32) {
        const int m = cnt[t];
        int mc = m;
#pragma unroll
        for (int off = 1; off < 32; off <<= 1)        // 32 active lanes only
            mc = max(mc, __shfl_xor(mc, off, 64));
        mc = __builtin_amdgcn_readfirstlane(mc);

        const int n = (bx & 255) * 32 + t;    // this lane's batch-local query

        unsigned long long md[KNN + 1];
#pragma unroll
        for (int s = 0; s <= KNN; ++s) md[s] = ~0ULL;

        if (mc <= CAP) {
            for (int cc = 0; cc < mc; ++cc) {
                unsigned long long key = (cc < m) ? coll[cc][t] : ~0ULL;
#pragma unroll
                for (int u = 0; u <= KNN; ++u) {
                    const bool lt = key < md[u];
                    const unsigned long long lo = lt ? key : md[u];
                    key = lt ? md[u] : key;
                    md[u] = lo;
                }
            }
        } else {
            // exact serial fallback (never expected): full rescan, inline w
            const float qx = cb[n * 3 + 0];
            const float qy = cb[n * 3 + 1];
            const float qz = cb[n * 3 + 2];
            const float qs = fmaf(qz, qz, fmaf(qy, qy, qx * qx));
            for (int j = 0; j < NPTS; ++j) {
                const float px = cb[j * 3 + 0];
                const float py = cb[j * 3 + 1];
                const float pz = cb[j * 3 + 2];
                const float pw = fmaf(pz, pz, fmaf(py, py, px * px));
                const float dot = fmaf(pz, qz, fmaf(py, qy, px * qx));
                const float d2 = fmaf(-2.0f, dot, qs + pw);
                const unsigned int fb = __float_as_uint(d2);
                const unsigned int mm =
                    fb ^ ((unsigned int)((int)fb >> 31) | 0x80000000u);
                unsigned long long key =
                    ((unsigned long long)mm << 13) | (unsigned long long)j;
                key = (j == n) ? ~0ULL : key;
#pragma unroll
                for (int u = 0; u <= KNN; ++u) {
                    const bool lt = key < md[u];
                    const unsigned long long lo = lt ? key : md[u];
                    key = lt ? md[u] : key;
                    md[u] = lo;
                }
            }
        }

        unsigned short* outp = knn_idx + ((size_t)b * NPTS + n) * KNN;
        int outc = 0;
#pragma unroll
        for (int u = 0; u <= KNN; ++u) {
            const int idx = (int)(md[u] & 8191u);
            if (outc < KNN && idx != n) outp[outc++] = (unsigned short)idx;
        }
    }
}

// ---------------------------------------------------------------------------
// Features + MLP — R18 config with QUAD-PARALLEL feature build (R19 change):
// lanes own 3/3/2/2 neighbors; mean/cov via quad partial sums + shfl_xor(1,2)
// reduces; eigen redundant on all 4 lanes, lane 0 writes. MLP part unchanged
// (best-measured R12/R14 layout).
// ---------------------------------------------------------------------------
__global__ __launch_bounds__(256) void feat_mlp_kernel(const float* __restrict__ cloud,
                                                       const float* __restrict__ W1,
                                                       const float* __restrict__ b1,
                                                       const float* __restrict__ W2,
                                                       const float* __restrict__ b2,
                                                       const unsigned short* __restrict__ knn_idx,
                                                       float* __restrict__ out) {
    __shared__ float w1s[NF * 68];            // padded stride
    __shared__ float b1s[HID];
    __shared__ float w2s[HID * 3];
    __shared__ float b2s[3];
    __shared__ float fs[64][NF + 1];          // stride 77

    const int t = threadIdx.x;
    for (int idx = t; idx < NF * HID; idx += 256)
        w1s[(idx >> 6) * 68 + (idx & 63)] = W1[idx];
    if (t < HID) b1s[t] = b1[t];
    if (t < HID * 3) w2s[t] = W2[t];
    if (t < 3) b2s[t] = b2[t];

    const int pl   = t >> 2;                  // point slot 0..63
    const int s    = t & 3;                   // quad sub-lane
    const int subh = t & 1;                   // hidden half
    const int subf = (t >> 1) & 1;            // feature half
    const int gid = blockIdx.x * 64 + pl;     // 0..32767
    const int b = gid >> 13;
    const int n = gid & (NPTS - 1);
    const float* cb = cloud + (size_t)b * NPTS * 3;

    // ---- quad-parallel feature build ----
    {
        const float cx = cb[n * 3 + 0];       // same addr across quad (broadcast)
        const float cy = cb[n * 3 + 1];
        const float cz = cb[n * 3 + 2];

        // neighbor ownership: s=0:{0,1,2} s=1:{3,4,5} s=2:{6,7} s=3:{8,9}
        const int kbase = (s == 0) ? 0 : (s == 1) ? 3 : (s == 2) ? 6 : 8;
        const int kcnt  = (s < 2) ? 3 : 2;

        float nx[3], ny[3], nz[3];
        const unsigned short* ki = knn_idx + (size_t)gid * KNN;
        for (int kk = 0; kk < kcnt; ++kk) {
            const int j = ki[kbase + kk];
            nx[kk] = cb[j * 3 + 0];
            ny[kk] = cb[j * 3 + 1];
            nz[kk] = cb[j * 3 + 2];
        }

        float* fr = fs[pl];
        if (s == 0) { fr[0] = cx; fr[1] = cy; fr[2] = cz; }
        for (int kk = 0; kk < kcnt; ++kk) {
            const int k = kbase + kk;
            fr[3 + 3 * k + 0] = nx[kk];
            fr[3 + 3 * k + 1] = ny[kk];
            fr[3 + 3 * k + 2] = nz[kk];
            const float rx = nx[kk] - cx, ry = ny[kk] - cy, rz = nz[kk] - cz;
            fr[33 + 3 * k + 0] = rx;
            fr[33 + 3 * k + 1] = ry;
            fr[33 + 3 * k + 2] = rz;
            fr[63 + k] = sqrtf(fmaf(rz, rz, fmaf(ry, ry, rx * rx)));
        }

        // quad-reduced mean
        float smx = 0.f, smy = 0.f, smz = 0.f;
        for (int kk = 0; kk < kcnt; ++kk) { smx += nx[kk]; smy += ny[kk]; smz += nz[kk]; }
#define QSUM(v) { v += __shfl_xor(v, 1, 64); v += __shfl_xor(v, 2, 64); }
        QSUM(smx); QSUM(smy); QSUM(smz);
        const float mx = smx * (1.0f / KNN);
        const float my = smy * (1.0f / KNN);
        const float mz = smz * (1.0f / KNN);

        // quad-reduced covariance partials
        float c00 = 0.f, c01 = 0.f, c02 = 0.f, c11 = 0.f, c12 = 0.f, c22 = 0.f;
        for (int kk = 0; kk < kcnt; ++kk) {
            const float ex = nx[kk] - mx, ey = ny[kk] - my, ez = nz[kk] - mz;
            c00 = fmaf(ex, ex, c00); c01 = fmaf(ex, ey, c01); c02 = fmaf(ex, ez, c02);
            c11 = fmaf(ey, ey, c11); c12 = fmaf(ey, ez, c12); c22 = fmaf(ez, ez, c22);
        }
        QSUM(c00); QSUM(c01); QSUM(c02); QSUM(c11); QSUM(c12); QSUM(c22);
#undef QSUM
        const float sc = 1.0f / (KNN - 1);
        c00 *= sc; c01 *= sc; c02 *= sc; c11 *= sc; c12 *= sc; c22 *= sc;

        // fp32 closed-form symmetric 3x3 eigenvalues (all 4 lanes, same time)
        const float qd = (c00 + c11 + c22) * (1.0f / 3.0f);
        const float pp1 = c01 * c01 + c02 * c02 + c12 * c12;
        const float d00 = c00 - qd, d11 = c11 - qd, d22 = c22 - qd;
        const float p2 = d00 * d00 + d11 * d11 + d22 * d22 + 2.0f * pp1;
        float l1, l2, l3;
        if (p2 < 1e-30f) {
            l1 = l2 = l3 = qd;
        } else {
            const float p = sqrtf(p2 * (1.0f / 6.0f));
            const float inv = 1.0f / p;
            const float e00 = d00 * inv, e11 = d11 * inv, e22 = d22 * inv;
            const float e01 = c01 * inv, e02 = c02 * inv, e12 = c12 * inv;
            float detB = e00 * (e11 * e22 - e12 * e12)
                       - e01 * (e01 * e22 - e12 * e02)
                       + e02 * (e01 * e12 - e11 * e02);
            float r = 0.5f * detB;
            r = fminf(1.0f, fmaxf(-1.0f, r));
            const float phi = acosf(r) * (1.0f / 3.0f);
            l1 = qd + 2.0f * p * __cosf(phi);                          // largest
            l3 = qd + 2.0f * p * __cosf(phi + 2.0943951023931953f);    // smallest
            l2 = 3.0f * qd - l1 - l3;
        }
        if (s == 0) {
            fr[73] = (l1 - l2) / l1;
            fr[74] = (l2 - l3) / l1;
            fr[75] = l3 / l1;
        }
    }

    __syncthreads();   // weights + features visible

    const float* fr = fs[pl];
    const int f0 = subf * 38;

    float h[32];
#pragma unroll
    for (int j = 0; j < 32; ++j) h[j] = (subf == 0) ? b1s[subh * 32 + j] : 0.0f;

#pragma unroll 2
    for (int ff = 0; ff < 38; ++ff) {
        const int f = f0 + ff;
        const float v = fr[f];
        const float4* w4 = reinterpret_cast<const float4*>(w1s + f * 68 + subh * 32);
#pragma unroll
        for (int j4 = 0; j4 < 8; ++j4) {
            const float4 w = w4[j4];
            h[4 * j4 + 0] = fmaf(v, w.x, h[4 * j4 + 0]);
            h[4 * j4 + 1] = fmaf(v, w.y, h[4 * j4 + 1]);
            h[4 * j4 + 2] = fmaf(v, w.z, h[4 * j4 + 2]);
            h[4 * j4 + 3] = fmaf(v, w.w, h[4 * j4 + 3]);
        }
    }

    // combine feature halves (lanes differing in bit 1)
#pragma unroll
    for (int j = 0; j < 32; ++j) h[j] += __shfl_xor(h[j], 2, 64);

    float o0 = 0.f, o1 = 0.f, o2 = 0.f;
#pragma unroll
    for (int j = 0; j < 32; ++j) {
        const float r = fmaxf(h[j], 0.0f);
        const int jj = subh * 32 + j;
        o0 = fmaf(r, w2s[jj * 3 + 0], o0);
        o1 = fmaf(r, w2s[jj * 3 + 1], o1);
        o2 = fmaf(r, w2s[jj * 3 + 2], o2);
    }
    // combine hidden halves (lanes differing in bit 0)
    o0 += __shfl_xor(o0, 1, 64);
    o1 += __shfl_xor(o1, 1, 64);
    o2 += __shfl_xor(o2, 1, 64);

    if ((t & 3) == 0) {
        float* op = out + (size_t)gid * 3;
        op[0] = fmaxf(o0 + b2s[0], 0.0f);
        op[1] = fmaxf(o1 + b2s[1], 0.0f);
        op[2] = fmaxf(o2 + b2s[2], 0.0f);
    }
}

extern "C" void kernel_launch(void* const* d_in, const int* in_sizes, int n_in,
                              void* d_out, int out_size, void* d_ws, size_t ws_size,
                              hipStream_t stream) {
    const float* cloud = (const float*)d_in[0];   // [4,8192,3]
    const float* W1    = (const float*)d_in[1];   // [76,64]
    const float* b1    = (const float*)d_in[2];   // [64]
    const float* W2    = (const float*)d_in[3];   // [64,3]
    const float* b2    = (const float*)d_in[4];   // [3]
    float* out = (float*)d_out;                   // [4,8192,3]

    unsigned short* knn = (unsigned short*)d_ws;  // 640 KB

    knn_kernel<<<dim3(1024), dim3(512), 0, stream>>>(cloud, knn);
    feat_mlp_kernel<<<dim3(512), dim3(256), 0, stream>>>(cloud, W1, b1, W2, b2, knn, out);
}

// Round 5
// 170.560 us; speedup vs baseline: 1.0039x; 1.0039x over previous
//
#include <hip/hip_runtime.h>
#include <math.h>

#define KNN    10
#define NPTS   8192
#define HID    64
#define NF     76
#define Q      16                // queries per wave
#define CAP    64                // pass-2 collection capacity per query
#define F32_INF __uint_as_float(0x7F800000u)

typedef float v2f __attribute__((ext_vector_type(2)));

__device__ __forceinline__ float rl(float v, int lane) {
    return __int_as_float(__builtin_amdgcn_readlane(__float_as_int(v), lane));
}

// ---------------------------------------------------------------------------
// R24: SoA transpose pre-kernel. The knn candidate stream was stride-12 AoS:
// each wave64 load touched 12 cache lines (36 line-touches/tile) on the CU's
// single TA/TD pipe -> ~36us of pure L1 service, the real plateau behind
// R21-R23's null/negative results (VALU -19% = no change; +prefetch depth =
// regression). SoA makes every candidate load 64x4B = 4 lines, coalesced.
// Values bit-identical (same floats, same fmaf chains, only addresses change).
// ---------------------------------------------------------------------------
__global__ __launch_bounds__(256) void soa_kernel(const float* __restrict__ cloud,
                                                  float* __restrict__ soa) {
    const int i = blockIdx.x * 256 + threadIdx.x;   // 0..32767 (grid exact)
    const float x = cloud[i * 3 + 0];
    const float y = cloud[i * 3 + 1];
    const float z = cloud[i * 3 + 2];
    soa[i]             = x;
    soa[4 * NPTS + i]  = y;
    soa[8 * NPTS + i]  = z;
}

// ---------------------------------------------------------------------------
// KNN — R18 structure, R21 SGPR queries, R22 packed FP32 + 1-deep prefetch
// (R23's 2-deep rotation reverted: rotation movs force same-iteration load
// completion, so depth never grew; it only added movs/VGPRs, -7%).
// R24: all loads from SoA arrays (stride-4 coalesced).
// Selection chain untouched (validated 10+ rounds): inline w, transposed
// scan, rank-11 chunk-minima threshold + 1e-3, exact R1-chain key rebuild,
// top-11 + filter.
// ---------------------------------------------------------------------------
__global__ __launch_bounds__(512) void knn_kernel(const float* __restrict__ soa,
                                                  unsigned short* __restrict__ knn_idx) {
    __shared__ unsigned long long coll[CAP][33];   // 16.9 KB
    __shared__ float pk[8][Q][17];                 // 8.7 KB
    __shared__ float tau_s[32];
    __shared__ int   cnt[32];

    const int t    = threadIdx.x;
    const int w    = t >> 6;                  // wave 0..7
    const int lane = t & 63;
    const int g    = w >> 2;                  // query group 0..1
    const int h    = w & 3;                   // candidate quarter 0..3
    const int bx   = blockIdx.x;              // 0..1023
    const int b    = bx >> 8;                 // batch
    const int n_base = (bx & 255) * 32 + g * Q;   // batch-local first query of group
    const int lq_base = g * Q;                // block-local query base
    const int cb0 = h * (NPTS / 4);           // candidate base for this wave

    const float* __restrict__ xs = soa + (size_t)b * NPTS;
    const float* __restrict__ ys = xs + 4 * NPTS;
    const float* __restrict__ zs = xs + 8 * NPTS;

    if (t < 32) cnt[t] = 0;                   // visible after barrier 1

    // ---- query coords -> SGPR pairs via readlane (R21/R22) ----
    v2f qx_p[8], qy_p[8], qz_p[8];
    {
        const int ql = n_base + (lane & 15);
        const float lx = xs[ql];
        const float ly = ys[ql];
        const float lz = zs[ql];
#pragma unroll
        for (int j = 0; j < 8; ++j) {
            qx_p[j] = (v2f){ rl(lx, 2 * j), rl(lx, 2 * j + 1) };
            qy_p[j] = (v2f){ rl(ly, 2 * j), rl(ly, 2 * j + 1) };
            qz_p[j] = (v2f){ rl(lz, 2 * j), rl(lz, 2 * j + 1) };
        }
    }

    // ---------------- pass 1: per-lane minima over this quarter ----------------
    v2f vmin2[8];
#pragma unroll
    for (int j = 0; j < 8; ++j) vmin2[j] = (v2f){ F32_INF, F32_INF };

    {
        float cx0 = xs[cb0 + lane];
        float cy0 = ys[cb0 + lane];
        float cz0 = zs[cb0 + lane];
        for (int ti = 0; ti < NPTS / 4 / 64; ++ti) {  // 32 tiles
            // branchless wrap-around prefetch (last iter reloads tile 0, dead)
            const int c1 = cb0 + (((ti + 1) & 31) * 64) + lane;
            const float nx0 = xs[c1];
            const float ny0 = ys[c1];
            const float nz0 = zs[c1];
            const float aw  = fmaf(cz0, cz0, fmaf(cy0, cy0, cx0 * cx0));  // prep expr
            const v2f aw2  = (v2f){ aw, aw };
            const v2f a2x2 = (v2f){ -2.0f * cx0, -2.0f * cx0 };
            const v2f a2y2 = (v2f){ -2.0f * cy0, -2.0f * cy0 };
            const v2f a2z2 = (v2f){ -2.0f * cz0, -2.0f * cz0 };
#pragma unroll
            for (int j = 0; j < 8; ++j) {
                const v2f v = __builtin_elementwise_fma(a2x2, qx_p[j],
                              __builtin_elementwise_fma(a2y2, qy_p[j],
                              __builtin_elementwise_fma(a2z2, qz_p[j], aw2)));
                vmin2[j] = __builtin_elementwise_min(vmin2[j], v);  // self included
            }
            cx0 = nx0; cy0 = ny0; cz0 = nz0;
        }
    }

#pragma unroll
    for (int qq = 0; qq < Q; ++qq) {
        float v = vmin2[qq >> 1][qq & 1];
        v = fminf(v, __shfl_xor(v, 32, 64));
        v = fminf(v, __shfl_xor(v, 16, 64));
        if (lane < 16) pk[w][qq][lane] = v;
    }
    __syncthreads();                          // barrier 1: pk + cnt visible

    // h==0 waves: 11th smallest of 64 chunk minima -> tau for group
    if (h == 0) {
        float md[KNN + 1];
#pragma unroll
        for (int s = 0; s <= KNN; ++s) md[s] = F32_INF;
        const int qsel = lane & 15;           // 4-way replicated
#pragma unroll
        for (int cc = 0; cc < 64; ++cc) {
            float d = pk[g * 4 + (cc >> 4)][qsel][cc & 15];
#pragma unroll
            for (int u = 0; u <= KNN; ++u) {
                const float lo = fminf(md[u], d);
                d = fmaxf(md[u], d);
                md[u] = lo;
            }
        }
        if (lane < 16) tau_s[lq_base + lane] = md[KNN] + 1e-3f;
    }
    __syncthreads();                          // barrier 2: tau visible

    float taum[Q];
    {
        const float tv = tau_s[lq_base + (lane & 15)];
#pragma unroll
        for (int qq = 0; qq < Q; ++qq) taum[qq] = rl(tv, qq);   // -> SGPRs
    }

    // ---------------- pass 2: collect hits incl. self (rare) ----------------
    {
        float cx2 = xs[cb0 + lane];
        float cy2 = ys[cb0 + lane];
        float cz2 = zs[cb0 + lane];
        int jcur = cb0 + lane;
        for (int ti = 0; ti < NPTS / 4 / 64; ++ti) {
            const int c1 = cb0 + (((ti + 1) & 31) * 64) + lane;
            const float nx2 = xs[c1];
            const float ny2 = ys[c1];
            const float nz2 = zs[c1];
            const float aw  = fmaf(cz2, cz2, fmaf(cy2, cy2, cx2 * cx2));
            const v2f aw2  = (v2f){ aw, aw };
            const v2f a2x2 = (v2f){ -2.0f * cx2, -2.0f * cx2 };
            const v2f a2y2 = (v2f){ -2.0f * cy2, -2.0f * cy2 };
            const v2f a2z2 = (v2f){ -2.0f * cz2, -2.0f * cz2 };
#pragma unroll
            for (int j = 0; j < 8; ++j) {
                const v2f v = __builtin_elementwise_fma(a2x2, qx_p[j],
                              __builtin_elementwise_fma(a2y2, qy_p[j],
                              __builtin_elementwise_fma(a2z2, qz_p[j], aw2)));
#pragma unroll
                for (int half = 0; half < 2; ++half) {
                    const int qq = 2 * j + half;
                    if (__builtin_expect(v[half] <= taum[qq], 0)) {
                        // EXACT key: R1-chain d2 expression on identical bits.
                        const float qx = qx_p[j][half];
                        const float qy = qy_p[j][half];
                        const float qz = qz_p[j][half];
                        const float qs = fmaf(qz, qz, fmaf(qy, qy, qx * qx));
                        const float dot = fmaf(cz2, qz, fmaf(cy2, qy, cx2 * qx));
                        const float d2 = fmaf(-2.0f, dot, qs + aw);
                        const unsigned int fb = __float_as_uint(d2);
                        const unsigned int m =
                            fb ^ ((unsigned int)((int)fb >> 31) | 0x80000000u);  // monotone
                        const unsigned long long key =
                            ((unsigned long long)m << 13) | (unsigned long long)(unsigned)jcur;
                        const int slot = atomicAdd(&cnt[lq_base + qq], 1);
                        if (slot < CAP) coll[slot][lq_base + qq] = key;
                    }
                }
            }
            cx2 = nx2; cy2 = ny2; cz2 = nz2;
            jcur += 64;
        }
    }
    __syncthreads();

    // ---------------- phase 3: top-11 bubble, filter self by index ----------
    if (t < 32) {
        const int m = cnt[t];
        int mc = m;
#pragma unroll
        for (int off = 1; off < 32; off <<= 1)        // 32 active lanes only
            mc = max(mc, __shfl_xor(mc, off, 64));
        mc = __builtin_amdgcn_readfirstlane(mc);

        const int n = (bx & 255) * 32 + t;    // this lane's batch-local query

        unsigned long long md[KNN + 1];
#pragma unroll
        for (int s = 0; s <= KNN; ++s) md[s] = ~0ULL;

        if (mc <= CAP) {
            for (int cc = 0; cc < mc; ++cc) {
                unsigned long long key = (cc < m) ? coll[cc][t] : ~0ULL;
#pragma unroll
                for (int u = 0; u <= KNN; ++u) {
                    const bool lt = key < md[u];
                    const unsigned long long lo = lt ? key : md[u];
                    key = lt ? md[u] : key;
                    md[u] = lo;
                }
            }
        } else {
            // exact serial fallback (never expected): full rescan (SoA reads,
            // identical float values)
            const float qx = xs[n];
            const float qy = ys[n];
            const float qz = zs[n];
            const float qs = fmaf(qz, qz, fmaf(qy, qy, qx * qx));
            for (int j = 0; j < NPTS; ++j) {
                const float px = xs[j];
                const float py = ys[j];
                const float pz = zs[j];
                const float pw = fmaf(pz, pz, fmaf(py, py, px * px));
                const float dot = fmaf(pz, qz, fmaf(py, qy, px * qx));
                const float d2 = fmaf(-2.0f, dot, qs + pw);
                const unsigned int fb = __float_as_uint(d2);
                const unsigned int mm =
                    fb ^ ((unsigned int)((int)fb >> 31) | 0x80000000u);
                unsigned long long key =
                    ((unsigned long long)mm << 13) | (unsigned long long)j;
                key = (j == n) ? ~0ULL : key;
#pragma unroll
                for (int u = 0; u <= KNN; ++u) {
                    const bool lt = key < md[u];
                    const unsigned long long lo = lt ? key : md[u];
                    key = lt ? md[u] : key;
                    md[u] = lo;
                }
            }
        }

        unsigned short* outp = knn_idx + ((size_t)b * NPTS + n) * KNN;
        int outc = 0;
#pragma unroll
        for (int u = 0; u <= KNN; ++u) {
            const int idx = (int)(md[u] & 8191u);
            if (outc < KNN && idx != n) outp[outc++] = (unsigned short)idx;
        }
    }
}

// ---------------------------------------------------------------------------
// Features + MLP — R18 config with QUAD-PARALLEL feature build (R19 change):
// lanes own 3/3/2/2 neighbors; mean/cov via quad partial sums + shfl_xor(1,2)
// reduces; eigen redundant on all 4 lanes, lane 0 writes. MLP part unchanged
// (best-measured R12/R14 layout). Stays on AoS cloud: random-index gathers
// touch 1 line/point in AoS vs 3 in SoA.
// ---------------------------------------------------------------------------
__global__ __launch_bounds__(256) void feat_mlp_kernel(const float* __restrict__ cloud,
                                                       const float* __restrict__ W1,
                                                       const float* __restrict__ b1,
                                                       const float* __restrict__ W2,
                                                       const float* __restrict__ b2,
                                                       const unsigned short* __restrict__ knn_idx,
                                                       float* __restrict__ out) {
    __shared__ float w1s[NF * 68];            // padded stride
    __shared__ float b1s[HID];
    __shared__ float w2s[HID * 3];
    __shared__ float b2s[3];
    __shared__ float fs[64][NF + 1];          // stride 77

    const int t = threadIdx.x;
    for (int idx = t; idx < NF * HID; idx += 256)
        w1s[(idx >> 6) * 68 + (idx & 63)] = W1[idx];
    if (t < HID) b1s[t] = b1[t];
    if (t < HID * 3) w2s[t] = W2[t];
    if (t < 3) b2s[t] = b2[t];

    const int pl   = t >> 2;                  // point slot 0..63
    const int s    = t & 3;                   // quad sub-lane
    const int subh = t & 1;                   // hidden half
    const int subf = (t >> 1) & 1;            // feature half
    const int gid = blockIdx.x * 64 + pl;     // 0..32767
    const int b = gid >> 13;
    const int n = gid & (NPTS - 1);
    const float* cb = cloud + (size_t)b * NPTS * 3;

    // ---- quad-parallel feature build ----
    {
        const float cx = cb[n * 3 + 0];       // same addr across quad (broadcast)
        const float cy = cb[n * 3 + 1];
        const float cz = cb[n * 3 + 2];

        // neighbor ownership: s=0:{0,1,2} s=1:{3,4,5} s=2:{6,7} s=3:{8,9}
        const int kbase = (s == 0) ? 0 : (s == 1) ? 3 : (s == 2) ? 6 : 8;
        const int kcnt  = (s < 2) ? 3 : 2;

        float nx[3], ny[3], nz[3];
        const unsigned short* ki = knn_idx + (size_t)gid * KNN;
        for (int kk = 0; kk < kcnt; ++kk) {
            const int j = ki[kbase + kk];
            nx[kk] = cb[j * 3 + 0];
            ny[kk] = cb[j * 3 + 1];
            nz[kk] = cb[j * 3 + 2];
        }

        float* fr = fs[pl];
        if (s == 0) { fr[0] = cx; fr[1] = cy; fr[2] = cz; }
        for (int kk = 0; kk < kcnt; ++kk) {
            const int k = kbase + kk;
            fr[3 + 3 * k + 0] = nx[kk];
            fr[3 + 3 * k + 1] = ny[kk];
            fr[3 + 3 * k + 2] = nz[kk];
            const float rx = nx[kk] - cx, ry = ny[kk] - cy, rz = nz[kk] - cz;
            fr[33 + 3 * k + 0] = rx;
            fr[33 + 3 * k + 1] = ry;
            fr[33 + 3 * k + 2] = rz;
            fr[63 + k] = sqrtf(fmaf(rz, rz, fmaf(ry, ry, rx * rx)));
        }

        // quad-reduced mean
        float smx = 0.f, smy = 0.f, smz = 0.f;
        for (int kk = 0; kk < kcnt; ++kk) { smx += nx[kk]; smy += ny[kk]; smz += nz[kk]; }
#define QSUM(v) { v += __shfl_xor(v, 1, 64); v += __shfl_xor(v, 2, 64); }
        QSUM(smx); QSUM(smy); QSUM(smz);
        const float mx = smx * (1.0f / KNN);
        const float my = smy * (1.0f / KNN);
        const float mz = smz * (1.0f / KNN);

        // quad-reduced covariance partials
        float c00 = 0.f, c01 = 0.f, c02 = 0.f, c11 = 0.f, c12 = 0.f, c22 = 0.f;
        for (int kk = 0; kk < kcnt; ++kk) {
            const float ex = nx[kk] - mx, ey = ny[kk] - my, ez = nz[kk] - mz;
            c00 = fmaf(ex, ex, c00); c01 = fmaf(ex, ey, c01); c02 = fmaf(ex, ez, c02);
            c11 = fmaf(ey, ey, c11); c12 = fmaf(ey, ez, c12); c22 = fmaf(ez, ez, c22);
        }
        QSUM(c00); QSUM(c01); QSUM(c02); QSUM(c11); QSUM(c12); QSUM(c22);
#undef QSUM
        const float sc = 1.0f / (KNN - 1);
        c00 *= sc; c01 *= sc; c02 *= sc; c11 *= sc; c12 *= sc; c22 *= sc;

        // fp32 closed-form symmetric 3x3 eigenvalues (all 4 lanes, same time)
        const float qd = (c00 + c11 + c22) * (1.0f / 3.0f);
        const float pp1 = c01 * c01 + c02 * c02 + c12 * c12;
        const float d00 = c00 - qd, d11 = c11 - qd, d22 = c22 - qd;
        const float p2 = d00 * d00 + d11 * d11 + d22 * d22 + 2.0f * pp1;
        float l1, l2, l3;
        if (p2 < 1e-30f) {
            l1 = l2 = l3 = qd;
        } else {
            const float p = sqrtf(p2 * (1.0f / 6.0f));
            const float inv = 1.0f / p;
            const float e00 = d00 * inv, e11 = d11 * inv, e22 = d22 * inv;
            const float e01 = c01 * inv, e02 = c02 * inv, e12 = c12 * inv;
            float detB = e00 * (e11 * e22 - e12 * e12)
                       - e01 * (e01 * e22 - e12 * e02)
                       + e02 * (e01 * e12 - e11 * e02);
            float r = 0.5f * detB;
            r = fminf(1.0f, fmaxf(-1.0f, r));
            const float phi = acosf(r) * (1.0f / 3.0f);
            l1 = qd + 2.0f * p * __cosf(phi);                          // largest
            l3 = qd + 2.0f * p * __cosf(phi + 2.0943951023931953f);    // smallest
            l2 = 3.0f * qd - l1 - l3;
        }
        if (s == 0) {
            fr[73] = (l1 - l2) / l1;
            fr[74] = (l2 - l3) / l1;
            fr[75] = l3 / l1;
        }
    }

    __syncthreads();   // weights + features visible

    const float* fr = fs[pl];
    const int f0 = subf * 38;

    float h[32];
#pragma unroll
    for (int j = 0; j < 32; ++j) h[j] = (subf == 0) ? b1s[subh * 32 + j] : 0.0f;

#pragma unroll 2
    for (int ff = 0; ff < 38; ++ff) {
        const int f = f0 + ff;
        const float v = fr[f];
        const float4* w4 = reinterpret_cast<const float4*>(w1s + f * 68 + subh * 32);
#pragma unroll
        for (int j4 = 0; j4 < 8; ++j4) {
            const float4 w = w4[j4];
            h[4 * j4 + 0] = fmaf(v, w.x, h[4 * j4 + 0]);
            h[4 * j4 + 1] = fmaf(v, w.y, h[4 * j4 + 1]);
            h[4 * j4 + 2] = fmaf(v, w.z, h[4 * j4 + 2]);
            h[4 * j4 + 3] = fmaf(v, w.w, h[4 * j4 + 3]);
        }
    }

    // combine feature halves (lanes differing in bit 1)
#pragma unroll
    for (int j = 0; j < 32; ++j) h[j] += __shfl_xor(h[j], 2, 64);

    float o0 = 0.f, o1 = 0.f, o2 = 0.f;
#pragma unroll
    for (int j = 0; j < 32; ++j) {
        const float r = fmaxf(h[j], 0.0f);
        const int jj = subh * 32 + j;
        o0 = fmaf(r, w2s[jj * 3 + 0], o0);
        o1 = fmaf(r, w2s[jj * 3 + 1], o1);
        o2 = fmaf(r, w2s[jj * 3 + 2], o2);
    }
    // combine hidden halves (lanes differing in bit 0)
    o0 += __shfl_xor(o0, 1, 64);
    o1 += __shfl_xor(o1, 1, 64);
    o2 += __shfl_xor(o2, 1, 64);

    if ((t & 3) == 0) {
        float* op = out + (size_t)gid * 3;
        op[0] = fmaxf(o0 + b2s[0], 0.0f);
        op[1] = fmaxf(o1 + b2s[1], 0.0f);
        op[2] = fmaxf(o2 + b2s[2], 0.0f);
    }
}

extern "C" void kernel_launch(void* const* d_in, const int* in_sizes, int n_in,
                              void* d_out, int out_size, void* d_ws, size_t ws_size,
                              hipStream_t stream) {
    const float* cloud = (const float*)d_in[0];   // [4,8192,3]
    const float* W1    = (const float*)d_in[1];   // [76,64]
    const float* b1    = (const float*)d_in[2];   // [64]
    const float* W2    = (const float*)d_in[3];   // [64,3]
    const float* b2    = (const float*)d_in[4];   // [3]
    float* out = (float*)d_out;                   // [4,8192,3]

    unsigned short* knn = (unsigned short*)d_ws;              // 640 KB
    float* soa = (float*)((char*)d_ws + 655360);              // 384 KB SoA x/y/z

    soa_kernel<<<dim3(128), dim3(256), 0, stream>>>(cloud, soa);
    knn_kernel<<<dim3(1024), dim3(512), 0, stream>>>(soa, knn);
    feat_mlp_kernel<<<dim3(512), dim3(256), 0, stream>>>(cloud, W1, b1, W2, b2, knn, out);
}